// Round 7
// baseline (2967.109 us; speedup 1.0000x reference)
//
#include <hip/hip_runtime.h>

#define Bdim 512
#define Tt   256
#define Ii   128
#define Hh   512
#define BM   16     // batch rows per group
#define NGRP 32
#define NSL  8      // column slices (WGs) per group

typedef __attribute__((ext_vector_type(4))) float f32x4;
typedef __attribute__((ext_vector_type(4))) unsigned u32x4;
typedef __attribute__((ext_vector_type(8))) short short8;
typedef unsigned long long u64;
typedef unsigned u32;

__device__ __forceinline__ unsigned short f2bf(float f) {
    u32 u = __builtin_bit_cast(u32, f);
    u += 0x7fffu + ((u >> 16) & 1u);   // round-to-nearest-even
    return (unsigned short)(u >> 16);
}

__device__ __forceinline__ short8 pack_bf8(f32x4 lo, f32x4 hi) {
    short8 r;
    r[0] = (short)f2bf(lo[0]); r[1] = (short)f2bf(lo[1]);
    r[2] = (short)f2bf(lo[2]); r[3] = (short)f2bf(lo[3]);
    r[4] = (short)f2bf(hi[0]); r[5] = (short)f2bf(hi[1]);
    r[6] = (short)f2bf(hi[2]); r[7] = (short)f2bf(hi[3]);
    return r;
}

// weight A-fragment: lane holds W[row][k..k+8), K-order: h-cols then x-cols
__device__ __forceinline__ short8 load_wfrag(const float* __restrict__ Whh,
                                             const float* __restrict__ Wih,
                                             int row, int k) {
    const float* p = (k < Hh) ? (Whh + row * Hh + k) : (Wih + row * Ii + (k - Hh));
    f32x4 lo = *(const f32x4*)p;
    f32x4 hi = *(const f32x4*)(p + 4);
    return pack_bf8(lo, hi);
}

__device__ __forceinline__ float sigm(float v)  { return 1.f / (1.f + __expf(-v)); }
__device__ __forceinline__ float tanhf_(float v){ return 1.f - 2.f / (__expf(2.f * v) + 1.f); }

__device__ __forceinline__ u64 aload(const u64* p) {
    return __hip_atomic_load(p, __ATOMIC_RELAXED, __HIP_MEMORY_SCOPE_AGENT);
}
__device__ __forceinline__ void astore(u64* p, u64 v) {
    __hip_atomic_store(p, v, __ATOMIC_RELAXED, __HIP_MEMORY_SCOPE_AGENT);
}
// quantum u64 = {word0 = bf16(col even)<<16 | tag, word1 = bf16(col odd)<<16 | tag}
// 8B store is atomic -> checking word0's tag validates the whole u64.
__device__ __forceinline__ u32 tagbad(u64 q, u32 wtag) {
    return ((u32)q ^ wtag) & 0xffffu;
}

// Exchange layout (u64 units): F[(buf*NGRP+g)*4096 + c4*32 + batch*2 + j]
// c4 = col/4 (0..127), j selects col pair {0,1} or {2,3}.

__global__ __launch_bounds__(256, 1)
void gru_persist(const float* __restrict__ x,   const float* __restrict__ Wih,
                 const float* __restrict__ Whh, const float* __restrict__ bih,
                 const float* __restrict__ bhh, const float* __restrict__ Wlin,
                 const float* __restrict__ blin, float* __restrict__ out,
                 u64* __restrict__ F)
{
    const int wg   = blockIdx.x;
    const int tid  = threadIdx.x;
    const int lane = tid & 63;
    const int w    = tid >> 6;          // wave 0..3
    // Keep a group's 8 slices on nearby CUs (perf heuristic only; correctness
    // does not depend on placement — exchange is agent-scope at the LLC).
    const int xcd8 = wg & 7, lg = (wg >> 3) & 3, sl = wg >> 5;
    const int gi  = xcd8 * 4 + lg;      // group 0..31
    const int b0  = gi * BM;
    const int jw  = sl * 64 + w * 16;   // this wave's 16 gate/h columns
    const int l15 = lane & 15;          // batch row within group (D col)
    const int cg  = lane >> 4;          // 4-col chunk / k-half selector
    const int kg8 = cg * 8;
    const int colg = jw + l15;          // gate row this lane holds weights for
    const int c4w  = sl * 16 + w * 4 + cg;   // write quantum column-block

    // biases for lane's 4 gate columns jw + cg*4 + i
    f32x4 brv, bzv, bxnv, bhnv;
#pragma unroll
    for (int i = 0; i < 4; ++i) {
        int c = jw + cg * 4 + i;
        brv[i]  = bih[c] + bhh[c];
        bzv[i]  = bih[Hh + c] + bhh[Hh + c];
        bxnv[i] = bih[2 * Hh + c];
        bhnv[i] = bhh[2 * Hh + c];
    }

    // ---- weight A-fragments, resident for the whole kernel ----
    short8 wR[20], wZ[20], wN[20];
#pragma unroll
    for (int kt = 0; kt < 20; ++kt) {
        int k = kt * 32 + kg8;
        wR[kt] = load_wfrag(Whh, Wih, colg, k);
        wZ[kt] = load_wfrag(Whh, Wih, Hh + colg, k);
        wN[kt] = load_wfrag(Whh, Wih, 2 * Hh + colg, k);
    }

    f32x4 hreg = {0.f, 0.f, 0.f, 0.f};  // own (batch=l15, cols jw+cg*4..+4) fp32 carry

    // x B-fragments for t=0, packed to bf16 immediately (16 regs live)
    short8 bx[4];
    {
        const float* xp = x + ((size_t)(b0 + l15) * Tt + 0) * Ii + kg8;
#pragma unroll
        for (int kt = 0; kt < 4; ++kt)
            bx[kt] = pack_bf8(*(const f32x4*)(xp + kt * 32),
                              *(const f32x4*)(xp + kt * 32 + 4));
    }

#pragma unroll 1
    for (int t = 0; t < Tt; ++t) {
        const int wb = t & 1, rb = wb ^ 1;

        f32x4 accR = {0,0,0,0}, accZ = {0,0,0,0}, accNH = {0,0,0,0}, accNX = {0,0,0,0};

        // ---- x-part MFMAs (A=W, B=x^T) from registers ----
#pragma unroll
        for (int kt = 0; kt < 4; ++kt) {
            accR  = __builtin_amdgcn_mfma_f32_16x16x32_bf16(wR[16 + kt], bx[kt], accR, 0, 0, 0);
            accZ  = __builtin_amdgcn_mfma_f32_16x16x32_bf16(wZ[16 + kt], bx[kt], accZ, 0, 0, 0);
            accNX = __builtin_amdgcn_mfma_f32_16x16x32_bf16(wN[16 + kt], bx[kt], accNX, 0, 0, 0);
        }

        // prefetch + pack x_{t+1}; the latency overlaps other waves' publish
        if (t + 1 < Tt) {
            const float* xp = x + ((size_t)(b0 + l15) * Tt + (t + 1)) * Ii + kg8;
#pragma unroll
            for (int kt = 0; kt < 4; ++kt)
                bx[kt] = pack_bf8(*(const f32x4*)(xp + kt * 32),
                                  *(const f32x4*)(xp + kt * 32 + 4));
        }

        if (t > 0) {
            const u64* Frb = F + (size_t)(rb * NGRP + gi) * 4096 + l15 * 2;
            const u32 wtag = (u32)(t - 1);
            u64 hq[64];
            // issue all 64 quantum loads (pipelined)
#pragma unroll
            for (int kt = 0; kt < 16; ++kt) {
                int o = (kt * 8 + cg * 2) * 32;
                hq[4 * kt + 0] = aload(Frb + o);
                hq[4 * kt + 1] = aload(Frb + o + 1);
                hq[4 * kt + 2] = aload(Frb + o + 32);
                hq[4 * kt + 3] = aload(Frb + o + 33);
            }
            // validate tags == t-1; reload stale quanta until all fresh (bounded)
            for (int spin = 0; spin < (1 << 14); ++spin) {
                u32 nbad = 0;
#pragma unroll
                for (int kt = 0; kt < 16; ++kt) {
                    int o = (kt * 8 + cg * 2) * 32;
#pragma unroll
                    for (int j = 0; j < 4; ++j) {
                        int q = 4 * kt + j;
                        int off = o + (j >> 1) * 32 + (j & 1);
                        if (tagbad(hq[q], wtag)) { hq[q] = aload(Frb + off); nbad = 1; }
                    }
                }
                if (!__any(nbad != 0)) break;   // nothing was stale this pass
            }

            // ---- h-part MFMAs: strip tags, pack 8 bf16, feed B operand ----
#pragma unroll
            for (int kt = 0; kt < 16; ++kt) {
                u32x4 pv;
#pragma unroll
                for (int j = 0; j < 4; ++j) {
                    u64 q = hq[4 * kt + j];
                    u32 lo = (u32)q, hi = (u32)(q >> 32);
                    pv[j] = (lo >> 16) | (hi & 0xffff0000u);
                }
                short8 bh = __builtin_bit_cast(short8, pv);
                accR  = __builtin_amdgcn_mfma_f32_16x16x32_bf16(wR[kt], bh, accR, 0, 0, 0);
                accZ  = __builtin_amdgcn_mfma_f32_16x16x32_bf16(wZ[kt], bh, accZ, 0, 0, 0);
                accNH = __builtin_amdgcn_mfma_f32_16x16x32_bf16(wN[kt], bh, accNH, 0, 0, 0);
            }
        }

        // ---- gates + state update (lane: batch=l15, cols jw+cg*4 .. +4) ----
        f32x4 hnew;
#pragma unroll
        for (int i = 0; i < 4; ++i) {
            float r = sigm(accR[i] + brv[i]);
            float z = sigm(accZ[i] + bzv[i]);
            float n = tanhf_(accNX[i] + bxnv[i] + r * (accNH[i] + bhnv[i]));
            hnew[i] = (1.f - z) * n + z * hreg[i];
        }
        hreg = hnew;

        // ---- publish: lane's 4 cols = one 16B quantum = 2 tagged u64 stores.
        //      No drain, no flag: the tag IS the flag. ----
        {
            u32 tg = (u32)t;
            u32 w0 = ((u32)f2bf(hnew[0]) << 16) | tg;
            u32 w1 = ((u32)f2bf(hnew[1]) << 16) | tg;
            u32 w2 = ((u32)f2bf(hnew[2]) << 16) | tg;
            u32 w3 = ((u32)f2bf(hnew[3]) << 16) | tg;
            u64* Fw = F + (size_t)(wb * NGRP + gi) * 4096 + (size_t)c4w * 32 + l15 * 2;
            astore(Fw,     (u64)w0 | ((u64)w1 << 32));
            astore(Fw + 1, (u64)w2 | ((u64)w3 << 32));
        }
        __builtin_amdgcn_sched_barrier(0);   // keep publish ahead of next poll
    }

    // ---- final linear: wave 0 of slice-0 WG computes out[b0..b0+15] ----
    if (sl == 0 && w == 0) {
        const u64* Frb = F + (size_t)(1 * NGRP + gi) * 4096 + l15 * 2;  // buf of t=255
        const u32 wtag = (u32)(Tt - 1);
        u64 hq[64];
#pragma unroll
        for (int q = 0; q < 32; ++q) {
            int o = (cg * 32 + q) * 32;
            hq[2 * q]     = aload(Frb + o);
            hq[2 * q + 1] = aload(Frb + o + 1);
        }
        for (int spin = 0; spin < (1 << 14); ++spin) {
            u32 nbad = 0;
#pragma unroll
            for (int q = 0; q < 32; ++q) {
                int o = (cg * 32 + q) * 32;
#pragma unroll
                for (int j = 0; j < 2; ++j) {
                    if (tagbad(hq[2 * q + j], wtag)) { hq[2 * q + j] = aload(Frb + o + j); nbad = 1; }
                }
            }
            if (!__any(nbad != 0)) break;
        }
        float sum = 0.f;
#pragma unroll
        for (int q = 0; q < 32; ++q) {
            int c4 = cg * 32 + q;
#pragma unroll
            for (int j = 0; j < 2; ++j) {
                u64 v = hq[2 * q + j];
                u32 lo = (u32)v, hi = (u32)(v >> 32);
                float f0 = __builtin_bit_cast(float, lo & 0xffff0000u);
                float f1 = __builtin_bit_cast(float, hi & 0xffff0000u);
                sum += f0 * Wlin[c4 * 4 + 2 * j] + f1 * Wlin[c4 * 4 + 2 * j + 1];
            }
        }
        sum += __shfl_xor(sum, 16);
        sum += __shfl_xor(sum, 32);
        if (lane < 16) out[b0 + l15] = sum + blin[0];
    }
}

extern "C" void kernel_launch(void* const* d_in, const int* in_sizes, int n_in,
                              void* d_out, int out_size, void* d_ws, size_t ws_size,
                              hipStream_t stream) {
    const float* x    = (const float*)d_in[0];
    const float* Wih  = (const float*)d_in[1];
    const float* Whh  = (const float*)d_in[2];
    const float* bih  = (const float*)d_in[3];
    const float* bhh  = (const float*)d_in[4];
    const float* Wlin = (const float*)d_in[5];
    const float* blin = (const float*)d_in[6];
    float* out  = (float*)d_out;

    u64* F = (u64*)d_ws;   // 2 bufs * 32 groups * 128 c4 * 16 batch * 16B = 2 MB
    const size_t fbytes = 2ull * NGRP * 128 * 16 * 16;
    // tags -> 0xFFFF (matches no step) each launch: kills cross-replay aliasing
    hipMemsetAsync(F, 0xFF, fbytes, stream);
    gru_persist<<<256, 256, 0, stream>>>(x, Wih, Whh, bih, bhh, Wlin, blin, out, F);
}